// Round 4
// baseline (440.832 us; speedup 1.0000x reference)
//
#include <hip/hip_runtime.h>
#include <hip/hip_bf16.h>
#include <math.h>

#define HH 128
#define WW 128
#define HWSZ (HH*WW)

typedef __attribute__((ext_vector_type(4))) short short4v;
typedef __attribute__((ext_vector_type(8))) short bfrag;   // 8 bf16
typedef __attribute__((ext_vector_type(4))) float f4;

__device__ inline unsigned short f2bf(float v) {
    unsigned u = __builtin_bit_cast(unsigned, v);
    unsigned r = u + 0x7fffu + ((u >> 16) & 1u);
    return (unsigned short)(r >> 16);
}
__device__ inline float bf2f(short s) {
    return __builtin_bit_cast(float, ((unsigned)(unsigned short)s) << 16);
}

// ---------------------------------------------------------------------------
// Weight prepack: fp32 W[oc][ic][3][3] -> bf16 A-fragments for
// mfma_f32_16x16x32_bf16:
// flat = ((((oct*(NIC/64)+c64)*9+tap)*2+icc32)*64+lane)*8+j
// oc = oct*16 + (lane&15); ic = c64*64 + icc32*32 + (lane>>4)*8 + j
// ---------------------------------------------------------------------------
__device__ inline void pack_frag(const float* __restrict__ w, short* __restrict__ dst,
                                 int i, int NIC, int NOC) {
    int j     = i & 7;
    int lane  = (i >> 3) & 63;
    int icc32 = (i >> 9) & 1;
    int tap   = (i >> 10) % 9;
    int rest  = (i >> 10) / 9;          // oct*(NIC/64) + c64
    int NC    = NIC >> 6;
    int c64   = rest % NC;
    int oct   = rest / NC;
    int oc    = oct * 16 + (lane & 15);
    int ic    = c64 * 64 + icc32 * 32 + (lane >> 4) * 8 + j;
    float v = 0.f;
    if (oc < NOC) v = w[((size_t)oc * NIC + ic) * 9 + tap];
    dst[i] = (short)f2bf(v);
}

#define SZ128 73728
#define SZ64  36864
#define SZDCN 36864

__global__ void pack_all_k(const float* __restrict__ w1, const float* __restrict__ w2,
                           const float* __restrict__ w3, const float* __restrict__ wom,
                           const float* __restrict__ wout, const float* __restrict__ wdcn,
                           short* __restrict__ ap)
{
    int i = blockIdx.x * 256 + threadIdx.x;
    if      (i < SZ128)                 pack_frag(w1,  ap,                          i,                   128, 64);
    else if (i < 2*SZ128)               pack_frag(w2,  ap + SZ128,                  i - SZ128,           128, 64);
    else if (i < 2*SZ128 + SZ64)        pack_frag(w3,  ap + 2*SZ128,                i - 2*SZ128,          64, 64);
    else if (i < 2*SZ128 + 2*SZ64)      pack_frag(wom, ap + 2*SZ128 + SZ64,         i - 2*SZ128 - SZ64,   64, 27);
    else if (i < 2*SZ128 + 3*SZ64)      pack_frag(wout,ap + 2*SZ128 + 2*SZ64,       i - 2*SZ128 - 2*SZ64, 64, 64);
    else if (i < 2*SZ128 + 3*SZ64 + SZDCN)
                                        pack_frag(wdcn,ap + 2*SZ128 + 3*SZ64,       i - 2*SZ128 - 3*SZ64, 64, 64);
}

// ---------------------------------------------------------------------------
// Transpose x (fp32, NCHW) -> xt (bf16, NHWC). Block = one (b,h) row.
// ---------------------------------------------------------------------------
__global__ __launch_bounds__(256) void xt_k(const float* __restrict__ x, short* __restrict__ xt)
{
    __shared__ short s_t[128][72];
    const int tid = threadIdx.x;
    const int h = blockIdx.x, b = blockIdx.y;
    for (int i = tid; i < 64 * 128; i += 256) {
        int c = i >> 7, w = i & 127;
        s_t[w][c] = (short)f2bf(x[((size_t)(b * 64 + c)) * HWSZ + h * WW + w]);
    }
    __syncthreads();
    for (int i = tid; i < 128 * 32; i += 256) {
        int w = i >> 5, cp = i & 31;
        unsigned pk = (unsigned)(unsigned short)s_t[w][cp * 2]
                    | ((unsigned)(unsigned short)s_t[w][cp * 2 + 1] << 16);
        *(unsigned*)&xt[(((size_t)(b * 128 + h) * 128 + w) * 64) + cp * 2] = pk;
    }
}

// ---------------------------------------------------------------------------
// MFMA implicit-GEMM 3x3 SAME conv.
// Waves = 4 pixel-quarters (32 px each); each wave computes NOCT oc-tiles
// (b-frag read once -> NOCT MFMAs). Rolling per-tap A-fragment prefetch.
// ---------------------------------------------------------------------------
template<int NIC, int NOC, int NOCT, int ACT>
__global__ __launch_bounds__(256, 2) void conv_mfma_k(
    const float* __restrict__ in1, const float* __restrict__ in2,
    const short* __restrict__ apack, const float* __restrict__ bias,
    float* __restrict__ out)
{
    constexpr int NC = NIC / 64;
    __shared__ short s_x[3][130][76];

    const int tid  = threadIdx.x;
    const int lane = tid & 63;
    const int wv   = tid >> 6;        // pixel quarter
    const int n16  = lane & 15;
    const int kq   = lane >> 4;
    const int h    = blockIdx.x;
    const int b    = blockIdx.y;

    f4 acc[NOCT][2];
#pragma unroll
    for (int t = 0; t < NOCT; ++t)
#pragma unroll
        for (int p = 0; p < 2; ++p) acc[t][p] = (f4){0.f, 0.f, 0.f, 0.f};

    const short* a_lane = apack + (size_t)lane * 8;

    for (int c64 = 0; c64 < NC; ++c64) {
        const float* src = (NIC == 128 && c64 == 1) ? in2 : in1;
        __syncthreads();
        for (int idx = tid; idx < 3 * 32 * 130; idx += 256) {
            int col = idx % 130;
            int t2  = idx / 130;
            int icp = t2 & 31;
            int dy  = t2 >> 5;
            int gy = h - 1 + dy, gx = col - 1;
            float v0 = 0.f, v1 = 0.f;
            if ((unsigned)gy < 128u && (unsigned)gx < 128u) {
                const float* p = src + ((size_t)(b * 64 + icp * 2)) * HWSZ + gy * WW + gx;
                v0 = p[0]; v1 = p[HWSZ];
            }
            unsigned pk = (unsigned)f2bf(v0) | ((unsigned)f2bf(v1) << 16);
            *(unsigned*)&s_x[dy][col][icp * 2] = pk;
        }
        __syncthreads();

        bfrag a_cur[2][NOCT], a_nxt[2][NOCT];
#pragma unroll
        for (int icc = 0; icc < 2; ++icc)
#pragma unroll
            for (int oct = 0; oct < NOCT; ++oct)
                a_cur[icc][oct] = *(const bfrag*)(a_lane +
                    ((((size_t)oct * NC + c64) * 9 + 0) * 2 + icc) * 512);

#pragma unroll
        for (int tap = 0; tap < 9; ++tap) {
            const int dy = tap / 3, dx = tap % 3;
            if (tap < 8) {
#pragma unroll
                for (int icc = 0; icc < 2; ++icc)
#pragma unroll
                    for (int oct = 0; oct < NOCT; ++oct)
                        a_nxt[icc][oct] = *(const bfrag*)(a_lane +
                            ((((size_t)oct * NC + c64) * 9 + (tap + 1)) * 2 + icc) * 512);
            }
#pragma unroll
            for (int icc = 0; icc < 2; ++icc) {
                const int icb = icc * 32 + kq * 8;
                bfrag bb[2];
#pragma unroll
                for (int p = 0; p < 2; ++p) {
                    const short* bp = &s_x[dy][wv * 32 + p * 16 + n16 + dx][icb];
                    short4v lo = *(const short4v*)bp;
                    short4v hi = *(const short4v*)(bp + 4);
                    bb[p] = __builtin_shufflevector(lo, hi, 0, 1, 2, 3, 4, 5, 6, 7);
                }
#pragma unroll
                for (int oct = 0; oct < NOCT; ++oct) {
                    acc[oct][0] = __builtin_amdgcn_mfma_f32_16x16x32_bf16(a_cur[icc][oct], bb[0], acc[oct][0], 0, 0, 0);
                    acc[oct][1] = __builtin_amdgcn_mfma_f32_16x16x32_bf16(a_cur[icc][oct], bb[1], acc[oct][1], 0, 0, 0);
                }
            }
            if (tap < 8) {
#pragma unroll
                for (int icc = 0; icc < 2; ++icc)
#pragma unroll
                    for (int oct = 0; oct < NOCT; ++oct)
                        a_cur[icc][oct] = a_nxt[icc][oct];
            }
        }
    }

#pragma unroll
    for (int oct = 0; oct < NOCT; ++oct) {
#pragma unroll
        for (int r = 0; r < 4; ++r) {
            int oc = oct * 16 + kq * 4 + r;
            if (oc < NOC) {
                float bv = bias[oc];
#pragma unroll
                for (int p = 0; p < 2; ++p) {
                    int col = wv * 32 + p * 16 + n16;
                    float v = acc[oct][p][r] + bv;
                    if (ACT == 1) v = (v >= 0.f) ? v : 0.1f * v;
                    if (ACT == 2) v = fmaxf(v, 0.f);
                    out[((size_t)(b * NOC + oc)) * HWSZ + h * WW + col] = v;
                }
            }
        }
    }
}

// ---------------------------------------------------------------------------
// DCN per-pixel bilinear params (computed ONCE per pixel, not per lane).
// ---------------------------------------------------------------------------
__device__ inline void dcn_params(const float* __restrict__ om, int b, int h, int half,
                                  int k, int tid, float (*s_pw)[4], int (*s_pi)[4])
{
    if (tid < 64) {
        int pl = tid;
        int pxg = half * 64 + pl;
        const float* omb = om + ((size_t)b * 27) * HWSZ + h * WW + pxg;
        float oy = omb[(size_t)k * HWSZ];
        float ox = omb[(size_t)(9 + k) * HWSZ];
        float mv = omb[(size_t)(18 + k) * HWSZ];
        mv = 1.f / (1.f + expf(-mv));
        float py = (float)(h - 1 + (k / 3)) + oy;
        float px = (float)(pxg - 1 + (k % 3)) + ox;
        float y0f = floorf(py), x0f = floorf(px);
        float ly = py - y0f, lx = px - x0f;
        int y0 = (int)y0f, x0 = (int)x0f;
        int y1 = y0 + 1, x1 = x0 + 1;
        float v00 = ((unsigned)y0 < 128u && (unsigned)x0 < 128u) ? 1.f : 0.f;
        float v01 = ((unsigned)y0 < 128u && (unsigned)x1 < 128u) ? 1.f : 0.f;
        float v10 = ((unsigned)y1 < 128u && (unsigned)x0 < 128u) ? 1.f : 0.f;
        float v11 = ((unsigned)y1 < 128u && (unsigned)x1 < 128u) ? 1.f : 0.f;
        int yc0 = min(max(y0, 0), 127), yc1 = min(max(y1, 0), 127);
        int xc0 = min(max(x0, 0), 127), xc1 = min(max(x1, 0), 127);
        s_pw[pl][0] = (1.f - ly) * (1.f - lx) * mv * v00;
        s_pw[pl][1] = (1.f - ly) * lx * mv * v01;
        s_pw[pl][2] = ly * (1.f - lx) * mv * v10;
        s_pw[pl][3] = ly * lx * mv * v11;
        s_pi[pl][0] = (yc0 * WW + xc0) * 64;
        s_pi[pl][1] = (yc0 * WW + xc1) * 64;
        s_pi[pl][2] = (yc1 * WW + xc0) * 64;
        s_pi[pl][3] = (yc1 * WW + xc1) * 64;
    }
}

// ---------------------------------------------------------------------------
// MFMA DCN v2. Block = half row (64 px), grid (HH*2, B).
// Phase A: per-pixel params once. Phase B: lane=channel coalesced sample.
// Phase C: 4 oc-tiles x 1 pixtile per wave, rolling A-frag prefetch.
// ---------------------------------------------------------------------------
__global__ __launch_bounds__(256, 2) void dcn_mfma_k(
    const short* __restrict__ xt, const float* __restrict__ om,
    const short* __restrict__ adcn, const float* __restrict__ bias,
    float* __restrict__ out)
{
    __shared__ __align__(16) short s_samp[64][72];
    __shared__ __align__(16) float s_pw[64][4];
    __shared__ __align__(16) int   s_pi[64][4];

    const int tid  = threadIdx.x;
    const int lane = tid & 63;
    const int wv   = tid >> 6;
    const int n16  = lane & 15;
    const int kq   = lane >> 4;
    const int bx   = blockIdx.x;
    const int h    = bx >> 1;
    const int half = bx & 1;
    const int b    = blockIdx.y;

    f4 acc[4];
#pragma unroll
    for (int t = 0; t < 4; ++t) acc[t] = (f4){0.f, 0.f, 0.f, 0.f};

    const short* a_lane = adcn + (size_t)lane * 8;
    const short* xb = xt + (size_t)b * HWSZ * 64;

    dcn_params(om, b, h, half, 0, tid, s_pw, s_pi);

    bfrag a_cur[2][4], a_nxt[2][4];
#pragma unroll
    for (int icc = 0; icc < 2; ++icc)
#pragma unroll
        for (int oct = 0; oct < 4; ++oct)
            a_cur[icc][oct] = *(const bfrag*)(a_lane + ((((size_t)oct * 9 + 0) * 2 + icc) * 512));

    for (int k = 0; k < 9; ++k) {
        __syncthreads();   // params(k) ready; prev MFMA reads of s_samp done
        // ---- phase B: sample 16 px per wave, lane = channel
#pragma unroll 4
        for (int i = 0; i < 16; ++i) {
            int pl = wv * 16 + i;
            float4 w = *(const float4*)s_pw[pl];
            int4  ix = *(const int4*)s_pi[pl];
            float v = w.x * bf2f(xb[ix.x + lane]) + w.y * bf2f(xb[ix.y + lane])
                    + w.z * bf2f(xb[ix.z + lane]) + w.w * bf2f(xb[ix.w + lane]);
            s_samp[pl][lane] = (short)f2bf(v);
        }
        __syncthreads();
        // ---- next tap's params + A-frags issued during MFMA region
        if (k < 8) {
            dcn_params(om, b, h, half, k + 1, tid, s_pw, s_pi);
#pragma unroll
            for (int icc = 0; icc < 2; ++icc)
#pragma unroll
                for (int oct = 0; oct < 4; ++oct)
                    a_nxt[icc][oct] = *(const bfrag*)(a_lane +
                        ((((size_t)oct * 9 + (k + 1)) * 2 + icc) * 512));
        }
        // ---- phase C: MFMA this tap (K=64 -> 2 ksteps)
#pragma unroll
        for (int icc = 0; icc < 2; ++icc) {
            const int icb = icc * 32 + kq * 8;
            const short* bp = &s_samp[wv * 16 + n16][icb];
            short4v lo = *(const short4v*)bp;
            short4v hi = *(const short4v*)(bp + 4);
            bfrag bb = __builtin_shufflevector(lo, hi, 0, 1, 2, 3, 4, 5, 6, 7);
#pragma unroll
            for (int oct = 0; oct < 4; ++oct)
                acc[oct] = __builtin_amdgcn_mfma_f32_16x16x32_bf16(a_cur[icc][oct], bb, acc[oct], 0, 0, 0);
        }
        if (k < 8) {
#pragma unroll
            for (int icc = 0; icc < 2; ++icc)
#pragma unroll
                for (int oct = 0; oct < 4; ++oct)
                    a_cur[icc][oct] = a_nxt[icc][oct];
        }
    }

    // ---- epilogue: bias, no activation
#pragma unroll
    for (int oct = 0; oct < 4; ++oct) {
#pragma unroll
        for (int r = 0; r < 4; ++r) {
            int oc = oct * 16 + kq * 4 + r;
            float bv = bias[oc];
            int col = half * 64 + wv * 16 + n16;
            out[((size_t)(b * 64 + oc)) * HWSZ + h * WW + col] = acc[oct][r] + bv;
        }
    }
}

// ---------------------------------------------------------------------------
extern "C" void kernel_launch(void* const* d_in, const int* in_sizes, int n_in,
                              void* d_out, int out_size, void* d_ws, size_t ws_size,
                              hipStream_t stream)
{
    const float* x      = (const float*)d_in[0];
    const float* xng    = (const float*)d_in[1];
    const float* offt   = (const float*)d_in[2];
    const float* w1     = (const float*)d_in[3];
    const float* b1     = (const float*)d_in[4];
    const float* w2     = (const float*)d_in[5];
    const float* b2     = (const float*)d_in[6];
    const float* w3     = (const float*)d_in[7];
    const float* b3     = (const float*)d_in[8];
    const float* wom    = (const float*)d_in[9];
    const float* bom    = (const float*)d_in[10];
    const float* wdcn   = (const float*)d_in[11];
    const float* bdcn   = (const float*)d_in[12];
    const float* wout   = (const float*)d_in[13];
    const float* bout   = (const float*)d_in[14];

    float* out0 = (float*)d_out;
    float* out1 = out0 + (size_t)4 * 64 * HWSZ;

    float* p1   = (float*)d_ws;                          // 4 MB
    float* p2   = p1 + (size_t)4 * 64 * HWSZ;            // 4 MB
    short* xt   = (short*)(p2 + (size_t)4 * 64 * HWSZ);  // 8.4 MB bf16 NHWC x
    short* apk  = xt + (size_t)4 * HWSZ * 64;

    short* a1p  = apk;
    short* a2p  = apk + SZ128;
    short* a3p  = apk + 2 * SZ128;
    short* aomp = apk + 2 * SZ128 + SZ64;
    short* aout = apk + 2 * SZ128 + 2 * SZ64;
    short* adcn = apk + 2 * SZ128 + 3 * SZ64;

    pack_all_k<<<(2 * SZ128 + 3 * SZ64 + SZDCN + 255) / 256, 256, 0, stream>>>(
        w1, w2, w3, wom, wout, wdcn, apk);
    xt_k<<<dim3(HH, 4), 256, 0, stream>>>(x, xt);

    dim3 cgrid(HH, 4);
    conv_mfma_k<128, 64, 4, 1><<<cgrid, 256, 0, stream>>>(x, xng, a1p, b1, p1);
    conv_mfma_k<128, 64, 4, 1><<<cgrid, 256, 0, stream>>>(p1, offt, a2p, b2, p2);
    conv_mfma_k<64, 64, 4, 1><<<cgrid, 256, 0, stream>>>(p2, nullptr, a3p, b3, out1);
    conv_mfma_k<64, 27, 2, 0><<<cgrid, 256, 0, stream>>>(out1, nullptr, aomp, bom, p1);
    dcn_mfma_k<<<dim3(HH * 2, 4), 256, 0, stream>>>(xt, p1, adcn, bdcn, p2);
    conv_mfma_k<64, 64, 4, 2><<<cgrid, 256, 0, stream>>>(p2, nullptr, aout, bout, out0);
}

// Round 5
// 272.628 us; speedup vs baseline: 1.6170x; 1.6170x over previous
//
#include <hip/hip_runtime.h>
#include <hip/hip_bf16.h>
#include <math.h>

#define HH 128
#define WW 128
#define HWSZ (HH*WW)

typedef __attribute__((ext_vector_type(4))) short short4v;
typedef __attribute__((ext_vector_type(8))) short bfrag;   // 8 bf16
typedef __attribute__((ext_vector_type(4))) float f4;

__device__ inline unsigned short f2bf(float v) {
    unsigned u = __builtin_bit_cast(unsigned, v);
    unsigned r = u + 0x7fffu + ((u >> 16) & 1u);
    return (unsigned short)(r >> 16);
}
__device__ inline float bf2f(short s) {
    return __builtin_bit_cast(float, ((unsigned)(unsigned short)s) << 16);
}
__device__ inline float bf2f_lo(unsigned u) { return __builtin_bit_cast(float, u << 16); }
__device__ inline float bf2f_hi(unsigned u) { return __builtin_bit_cast(float, u & 0xffff0000u); }

// ---------------------------------------------------------------------------
// Weight prepack: fp32 W[oc][ic][3][3] -> bf16 A-fragments, K-chunk = 32.
// frag f = ((oct*NCH + c32)*9 + tap); element = f*512 + lane*8 + j
// oc = oct*16 + (lane&15); ic = c32*32 + (lane>>4)*8 + j
// ---------------------------------------------------------------------------
__device__ inline void pack_frag(const float* __restrict__ w, short* __restrict__ dst,
                                 int i, int NIC, int NOC) {
    int j    = i & 7;
    int lane = (i >> 3) & 63;
    int f    = i >> 9;
    int tap  = f % 9;
    int g    = f / 9;
    int NCH  = NIC >> 5;
    int c32  = g % NCH;
    int oct  = g / NCH;
    int oc   = oct * 16 + (lane & 15);
    int ic   = c32 * 32 + ((lane >> 4) & 3) * 8 + j;
    float v = 0.f;
    if (oc < NOC) v = w[((size_t)oc * NIC + ic) * 9 + tap];
    dst[i] = (short)f2bf(v);
}

#define SZ128 73728
#define SZ64  36864

__global__ void pack_all_k(const float* __restrict__ w1, const float* __restrict__ w2,
                           const float* __restrict__ w3, const float* __restrict__ wom,
                           const float* __restrict__ wout, const float* __restrict__ wdcn,
                           short* __restrict__ ap)
{
    int i = blockIdx.x * 256 + threadIdx.x;
    if      (i < SZ128)                  pack_frag(w1,  ap,                          i,                    128, 64);
    else if (i < 2*SZ128)                pack_frag(w2,  ap + SZ128,                  i - SZ128,            128, 64);
    else if (i < 2*SZ128 + SZ64)         pack_frag(w3,  ap + 2*SZ128,                i - 2*SZ128,           64, 64);
    else if (i < 2*SZ128 + 2*SZ64)       pack_frag(wom, ap + 2*SZ128 + SZ64,         i - 2*SZ128 - SZ64,    64, 27);
    else if (i < 2*SZ128 + 3*SZ64)       pack_frag(wout,ap + 2*SZ128 + 2*SZ64,       i - 2*SZ128 - 2*SZ64,  64, 64);
    else if (i < 2*SZ128 + 4*SZ64)       pack_frag(wdcn,ap + 2*SZ128 + 3*SZ64,       i - 2*SZ128 - 3*SZ64,  64, 64);
}

// ---------------------------------------------------------------------------
// NCHW fp32 -> NHWC bf16 (stride 64). Block = one (b,h) row.
// ---------------------------------------------------------------------------
__global__ __launch_bounds__(256) void nhwc_k(const float* __restrict__ x, short* __restrict__ xt)
{
    __shared__ short s_t[128][72];
    const int tid = threadIdx.x;
    const int h = blockIdx.x, b = blockIdx.y;
    for (int i = tid; i < 64 * 128; i += 256) {
        int c = i >> 7, w = i & 127;
        s_t[w][c] = (short)f2bf(x[((size_t)(b * 64 + c)) * HWSZ + h * WW + w]);
    }
    __syncthreads();
    for (int i = tid; i < 128 * 32; i += 256) {
        int w = i >> 5, cp = i & 31;
        unsigned pk = (unsigned)(unsigned short)s_t[w][cp * 2]
                    | ((unsigned)(unsigned short)s_t[w][cp * 2 + 1] << 16);
        *(unsigned*)&xt[(((size_t)(b * 128 + h) * 128 + w) * 64) + cp * 2] = pk;
    }
}

// ---------------------------------------------------------------------------
// MFMA implicit-GEMM 3x3 SAME conv over NHWC bf16, K-chunk = 32.
// Block = one (b,h) row, 4 waves = 2 oc-halves (wo) x 2 px-halves (wp).
// LDS 31 KB -> 4+ blocks/CU. B-fragment = single aligned ds_read_b128.
// ---------------------------------------------------------------------------
template<int NIC, int NOC, int OCS, int ACT, bool WH, bool WC>
__global__ __launch_bounds__(256, 4) void conv_k(
    const short* __restrict__ in1, const short* __restrict__ in2,
    const short* __restrict__ apack, const float* __restrict__ bias,
    short* __restrict__ outh, float* __restrict__ outc)
{
    constexpr int NCH = NIC / 32;
    __shared__ short s_x[3][130][40];   // [row][px+halo][32ch + pad] (80B stride)

    const int tid  = threadIdx.x;
    const int lane = tid & 63;
    const int wv   = tid >> 6;
    const int wo   = wv & 1;
    const int wp   = wv >> 1;
    const int n16  = lane & 15;
    const int kq   = lane >> 4;
    const int h    = blockIdx.x;
    const int b    = blockIdx.y;

    f4 acc[2][4];
#pragma unroll
    for (int t = 0; t < 2; ++t)
#pragma unroll
        for (int p = 0; p < 4; ++p) acc[t][p] = (f4){0.f, 0.f, 0.f, 0.f};

    const short* a_lane = apack + (size_t)lane * 8;

    for (int cc = 0; cc < NCH; ++cc) {
        const short* src; int c0;
        if (NIC == 128 && cc >= 2) { src = in2; c0 = (cc - 2) * 32; }
        else                       { src = in1; c0 = cc * 32; }
        __syncthreads();
        // stage 3 rows x 130 px x 32 ch, 16B per thread-iter
        for (int i = tid; i < 1560; i += 256) {
            int row = i / 520, rem = i % 520;
            int px = rem >> 2, q = rem & 3;
            int gy = h - 1 + row, gx = px - 1;
            int4 v = {0, 0, 0, 0};
            if ((unsigned)gy < 128u && (unsigned)gx < 128u)
                v = *(const int4*)&src[(((size_t)(b * 128 + gy)) * 128 + gx) * 64 + c0 + q * 8];
            *(int4*)&s_x[row][px][q * 8] = v;
        }
        __syncthreads();

        if (wo * 32 < NOC) {
#pragma unroll
            for (int tap = 0; tap < 9; ++tap) {
                const int dy = tap / 3, dx = tap % 3;
                bfrag a0 = *(const bfrag*)(a_lane + (size_t)(((wo * 2 + 0) * NCH + cc) * 9 + tap) * 512);
                bfrag a1 = *(const bfrag*)(a_lane + (size_t)(((wo * 2 + 1) * NCH + cc) * 9 + tap) * 512);
#pragma unroll
                for (int p = 0; p < 4; ++p) {
                    bfrag bb = *(const bfrag*)&s_x[dy][wp * 64 + p * 16 + n16 + dx][kq * 8];
                    acc[0][p] = __builtin_amdgcn_mfma_f32_16x16x32_bf16(a0, bb, acc[0][p], 0, 0, 0);
                    acc[1][p] = __builtin_amdgcn_mfma_f32_16x16x32_bf16(a1, bb, acc[1][p], 0, 0, 0);
                }
            }
        }
    }

    // epilogue: C/D layout col=lane&15, row=(lane>>4)*4+reg; 4 consecutive oc/lane
#pragma unroll
    for (int oct = 0; oct < 2; ++oct) {
        int oc0 = wo * 32 + oct * 16 + kq * 4;
        if (oc0 < NOC) {
            float4 bv = *(const float4*)&bias[oc0];
#pragma unroll
            for (int p = 0; p < 4; ++p) {
                int col = wp * 64 + p * 16 + n16;
                float v0 = acc[oct][p][0] + bv.x;
                float v1 = acc[oct][p][1] + bv.y;
                float v2 = acc[oct][p][2] + bv.z;
                float v3 = acc[oct][p][3] + bv.w;
                if (ACT == 1) {
                    v0 = (v0 >= 0.f) ? v0 : 0.1f * v0;
                    v1 = (v1 >= 0.f) ? v1 : 0.1f * v1;
                    v2 = (v2 >= 0.f) ? v2 : 0.1f * v2;
                    v3 = (v3 >= 0.f) ? v3 : 0.1f * v3;
                }
                if (ACT == 2) {
                    v0 = fmaxf(v0, 0.f); v1 = fmaxf(v1, 0.f);
                    v2 = fmaxf(v2, 0.f); v3 = fmaxf(v3, 0.f);
                }
                if (WH) {
                    uint2 pk;
                    pk.x = (unsigned)f2bf(v0) | ((unsigned)f2bf(v1) << 16);
                    pk.y = (unsigned)f2bf(v2) | ((unsigned)f2bf(v3) << 16);
                    *(uint2*)&outh[(((size_t)(b * 128 + h)) * 128 + col) * OCS + oc0] = pk;
                }
                if (WC) {
                    size_t base = ((size_t)b * NOC) * HWSZ + h * WW + col;
                    outc[base + (size_t)(oc0 + 0) * HWSZ] = v0;
                    outc[base + (size_t)(oc0 + 1) * HWSZ] = v1;
                    outc[base + (size_t)(oc0 + 2) * HWSZ] = v2;
                    outc[base + (size_t)(oc0 + 3) * HWSZ] = v3;
                }
            }
        }
    }
}

// ---------------------------------------------------------------------------
// DCN per-pixel bilinear params from NHWC bf16 om (stride 32), once per px.
// ---------------------------------------------------------------------------
__device__ inline void dcn_params(const short* __restrict__ omb, int h, int k, int tid,
                                  float (*s_pw)[4], int (*s_pi)[4])
{
    if (tid < 128) {
        int pix = tid;
        const short* o = omb + pix * 32;
        float oy = bf2f(o[k]);
        float ox = bf2f(o[9 + k]);
        float mv = bf2f(o[18 + k]);
        mv = 1.f / (1.f + expf(-mv));
        float py = (float)(h - 1 + (k / 3)) + oy;
        float px = (float)(pix - 1 + (k % 3)) + ox;
        float y0f = floorf(py), x0f = floorf(px);
        float ly = py - y0f, lx = px - x0f;
        int y0 = (int)y0f, x0 = (int)x0f;
        int y1 = y0 + 1, x1 = x0 + 1;
        float v00 = ((unsigned)y0 < 128u && (unsigned)x0 < 128u) ? 1.f : 0.f;
        float v01 = ((unsigned)y0 < 128u && (unsigned)x1 < 128u) ? 1.f : 0.f;
        float v10 = ((unsigned)y1 < 128u && (unsigned)x0 < 128u) ? 1.f : 0.f;
        float v11 = ((unsigned)y1 < 128u && (unsigned)x1 < 128u) ? 1.f : 0.f;
        int yc0 = min(max(y0, 0), 127), yc1 = min(max(y1, 0), 127);
        int xc0 = min(max(x0, 0), 127), xc1 = min(max(x1, 0), 127);
        s_pw[pix][0] = (1.f - ly) * (1.f - lx) * mv * v00;
        s_pw[pix][1] = (1.f - ly) * lx * mv * v01;
        s_pw[pix][2] = ly * (1.f - lx) * mv * v10;
        s_pw[pix][3] = ly * lx * mv * v11;
        s_pi[pix][0] = (yc0 * WW + xc0) * 64;
        s_pi[pix][1] = (yc0 * WW + xc1) * 64;
        s_pi[pix][2] = (yc1 * WW + xc0) * 64;
        s_pi[pix][3] = (yc1 * WW + xc1) * 64;
    }
}

// ---------------------------------------------------------------------------
// MFMA DCN v3. Block = full row (128 px). Sampling: lane = (pixel-pair,
// ch-pair) -> 4B/lane fully-active corner loads. MFMA: wo x wp split.
// ---------------------------------------------------------------------------
__global__ __launch_bounds__(256, 4) void dcn_k(
    const short* __restrict__ xt, const short* __restrict__ om,
    const short* __restrict__ adcn, const float* __restrict__ bias,
    short* __restrict__ outh)
{
    __shared__ short s_samp[128][72];   // 144B px stride: 16B-aligned, 2-way banks
    __shared__ float s_pw[128][4];
    __shared__ int   s_pi[128][4];

    const int tid  = threadIdx.x;
    const int lane = tid & 63;
    const int wv   = tid >> 6;
    const int wo   = wv & 1;
    const int wp   = wv >> 1;
    const int n16  = lane & 15;
    const int kq   = lane >> 4;
    const int h    = blockIdx.x;
    const int b    = blockIdx.y;

    f4 acc[2][4];
#pragma unroll
    for (int t = 0; t < 2; ++t)
#pragma unroll
        for (int p = 0; p < 4; ++p) acc[t][p] = (f4){0.f, 0.f, 0.f, 0.f};

    const short* a_lane = adcn + (size_t)lane * 8;
    const short* xb  = xt + (size_t)b * HWSZ * 64;
    const short* omb = om + ((size_t)(b * 128 + h)) * 128 * 32;

    dcn_params(omb, h, 0, tid, s_pw, s_pi);

    const int pp = lane >> 5;      // pixel-pair half
    const int cp = lane & 31;      // channel pair

    for (int k = 0; k < 9; ++k) {
        __syncthreads();   // params(k) visible; MFMA(k-1) done with s_samp
#pragma unroll 4
        for (int i = 0; i < 16; ++i) {
            int pix = i * 8 + wv * 2 + pp;
            float4 w = *(const float4*)s_pw[pix];
            int4  ix = *(const int4*)s_pi[pix];
            unsigned u00 = *(const unsigned*)&xb[ix.x + cp * 2];
            unsigned u01 = *(const unsigned*)&xb[ix.y + cp * 2];
            unsigned u10 = *(const unsigned*)&xb[ix.z + cp * 2];
            unsigned u11 = *(const unsigned*)&xb[ix.w + cp * 2];
            float lo = w.x * bf2f_lo(u00) + w.y * bf2f_lo(u01) + w.z * bf2f_lo(u10) + w.w * bf2f_lo(u11);
            float hi = w.x * bf2f_hi(u00) + w.y * bf2f_hi(u01) + w.z * bf2f_hi(u10) + w.w * bf2f_hi(u11);
            *(unsigned*)&s_samp[pix][cp * 2] = (unsigned)f2bf(lo) | ((unsigned)f2bf(hi) << 16);
        }
        __syncthreads();
        if (k < 8) dcn_params(omb, h, k + 1, tid, s_pw, s_pi);
#pragma unroll
        for (int ks = 0; ks < 2; ++ks) {
            bfrag a0 = *(const bfrag*)(a_lane + (size_t)(((wo * 2 + 0) * 2 + ks) * 9 + k) * 512);
            bfrag a1 = *(const bfrag*)(a_lane + (size_t)(((wo * 2 + 1) * 2 + ks) * 9 + k) * 512);
#pragma unroll
            for (int p = 0; p < 4; ++p) {
                bfrag bb = *(const bfrag*)&s_samp[wp * 64 + p * 16 + n16][ks * 32 + kq * 8];
                acc[0][p] = __builtin_amdgcn_mfma_f32_16x16x32_bf16(a0, bb, acc[0][p], 0, 0, 0);
                acc[1][p] = __builtin_amdgcn_mfma_f32_16x16x32_bf16(a1, bb, acc[1][p], 0, 0, 0);
            }
        }
    }

    // epilogue: NHWC bf16, stride 64, no activation
#pragma unroll
    for (int oct = 0; oct < 2; ++oct) {
        int oc0 = wo * 32 + oct * 16 + kq * 4;
        float4 bv = *(const float4*)&bias[oc0];
#pragma unroll
        for (int p = 0; p < 4; ++p) {
            int col = wp * 64 + p * 16 + n16;
            uint2 pk;
            pk.x = (unsigned)f2bf(acc[oct][p][0] + bv.x) | ((unsigned)f2bf(acc[oct][p][1] + bv.y) << 16);
            pk.y = (unsigned)f2bf(acc[oct][p][2] + bv.z) | ((unsigned)f2bf(acc[oct][p][3] + bv.w) << 16);
            *(uint2*)&outh[(((size_t)(b * 128 + h)) * 128 + col) * 64 + oc0] = pk;
        }
    }
}

// ---------------------------------------------------------------------------
extern "C" void kernel_launch(void* const* d_in, const int* in_sizes, int n_in,
                              void* d_out, int out_size, void* d_ws, size_t ws_size,
                              hipStream_t stream)
{
    const float* x      = (const float*)d_in[0];
    const float* xng    = (const float*)d_in[1];
    const float* offt   = (const float*)d_in[2];
    const float* w1     = (const float*)d_in[3];
    const float* b1     = (const float*)d_in[4];
    const float* w2     = (const float*)d_in[5];
    const float* b2     = (const float*)d_in[6];
    const float* w3     = (const float*)d_in[7];
    const float* b3     = (const float*)d_in[8];
    const float* wom    = (const float*)d_in[9];
    const float* bom    = (const float*)d_in[10];
    const float* wdcn   = (const float*)d_in[11];
    const float* bdcn   = (const float*)d_in[12];
    const float* wout   = (const float*)d_in[13];
    const float* bout   = (const float*)d_in[14];

    float* out0 = (float*)d_out;
    float* out1 = out0 + (size_t)4 * 64 * HWSZ;

    const size_t NB = (size_t)4 * HWSZ * 64;   // elements per NHWC bf16 tensor
    short* xtx = (short*)d_ws;        // x NHWC (conv1 + dcn)
    short* xtn = xtx + NB;            // x_neigh NHWC -> later o2 -> later align
    short* xto = xtn + NB;            // offset_t NHWC -> later om (stride 32)
    short* o1  = xto + NB;            // offset_1 -> later o3
    short* apk = o1 + NB;

    short* o2    = xtn;
    short* o3    = o1;
    short* omb   = xto;
    short* align = xtn;

    short* a1p  = apk;
    short* a2p  = apk + SZ128;
    short* a3p  = apk + 2 * SZ128;
    short* aomp = apk + 2 * SZ128 + SZ64;
    short* aout = apk + 2 * SZ128 + 2 * SZ64;
    short* adcn = apk + 2 * SZ128 + 3 * SZ64;

    pack_all_k<<<(2 * SZ128 + 4 * SZ64 + 255) / 256, 256, 0, stream>>>(
        w1, w2, w3, wom, wout, wdcn, apk);
    dim3 rgrid(HH, 4);
    nhwc_k<<<rgrid, 256, 0, stream>>>(x,    xtx);
    nhwc_k<<<rgrid, 256, 0, stream>>>(xng,  xtn);
    nhwc_k<<<rgrid, 256, 0, stream>>>(offt, xto);

    // offset_1 = lrelu(conv(cat(x, x_neigh)))
    conv_k<128, 64, 64, 1, true, false><<<rgrid, 256, 0, stream>>>(xtx, xtn, a1p, b1, o1, nullptr);
    // offset_2 = lrelu(conv(cat(offset_1, offset_t)))
    conv_k<128, 64, 64, 1, true, false><<<rgrid, 256, 0, stream>>>(o1, xto, a2p, b2, o2, nullptr);
    // offset = lrelu(conv(offset_2)) -> NHWC for conv4 + NCHW fp32 output 1
    conv_k<64, 64, 64, 1, true, true><<<rgrid, 256, 0, stream>>>(o2, nullptr, a3p, b3, o3, out1);
    // om = conv(offset), 27 ch, NHWC stride 32
    conv_k<64, 27, 32, 0, true, false><<<rgrid, 256, 0, stream>>>(o3, nullptr, aomp, bom, omb, nullptr);
    // align = dcn_core(x, offsets, mask) -> NHWC bf16
    dcn_k<<<rgrid, 256, 0, stream>>>(xtx, omb, adcn, bdcn, align);
    // out = relu(conv(align)) -> NCHW fp32 output 0
    conv_k<64, 64, 64, 2, false, true><<<rgrid, 256, 0, stream>>>(align, nullptr, aout, bout, nullptr, out0);
}

// Round 7
// 249.622 us; speedup vs baseline: 1.7660x; 1.0922x over previous
//
#include <hip/hip_runtime.h>
#include <hip/hip_bf16.h>
#include <math.h>

#define HH 128
#define WW 128
#define HWSZ (HH*WW)

typedef __attribute__((ext_vector_type(8))) short bfrag;   // 8 bf16
typedef __attribute__((ext_vector_type(4))) float f4;

__device__ inline unsigned short f2bf(float v) {
    unsigned u = __builtin_bit_cast(unsigned, v);
    unsigned r = u + 0x7fffu + ((u >> 16) & 1u);
    return (unsigned short)(r >> 16);
}
__device__ inline float bf2f(short s) {
    return __builtin_bit_cast(float, ((unsigned)(unsigned short)s) << 16);
}
__device__ inline float bf2f_lo(unsigned u) { return __builtin_bit_cast(float, u << 16); }
__device__ inline float bf2f_hi(unsigned u) { return __builtin_bit_cast(float, u & 0xffff0000u); }

// ---------------------------------------------------------------------------
// Weight prepack: fp32 W[oc][ic][3][3] -> bf16 A-fragments, K-chunk = 32.
// frag f = ((oct*(NIC/32) + c32)*9 + tap); element = f*512 + lane*8 + j
// oc = oct*16 + (lane&15); ic = c32*32 + (lane>>4)*8 + j
// ---------------------------------------------------------------------------
__device__ inline void pack_frag(const float* __restrict__ w, short* __restrict__ dst,
                                 int i, int NIC, int NOC) {
    int j    = i & 7;
    int lane = (i >> 3) & 63;
    int f    = i >> 9;
    int tap  = f % 9;
    int g    = f / 9;
    int NCH  = NIC >> 5;
    int c32  = g % NCH;
    int oct  = g / NCH;
    int oc   = oct * 16 + (lane & 15);
    int ic   = c32 * 32 + ((lane >> 4) & 3) * 8 + j;
    float v = 0.f;
    if (oc < NOC) v = w[((size_t)oc * NIC + ic) * 9 + tap];
    dst[i] = (short)f2bf(v);
}

#define SZ128 73728
#define SZ64  36864

__global__ void pack_all_k(const float* __restrict__ w1, const float* __restrict__ w2,
                           const float* __restrict__ w3, const float* __restrict__ wom,
                           const float* __restrict__ wout, const float* __restrict__ wdcn,
                           short* __restrict__ ap)
{
    int i = blockIdx.x * 256 + threadIdx.x;
    if      (i < SZ128)                  pack_frag(w1,  ap,                          i,                    128, 64);
    else if (i < 2*SZ128)                pack_frag(w2,  ap + SZ128,                  i - SZ128,            128, 64);
    else if (i < 2*SZ128 + SZ64)         pack_frag(w3,  ap + 2*SZ128,                i - 2*SZ128,           64, 64);
    else if (i < 2*SZ128 + 2*SZ64)       pack_frag(wom, ap + 2*SZ128 + SZ64,         i - 2*SZ128 - SZ64,    64, 27);
    else if (i < 2*SZ128 + 3*SZ64)       pack_frag(wout,ap + 2*SZ128 + 2*SZ64,       i - 2*SZ128 - 2*SZ64,  64, 64);
    else if (i < 2*SZ128 + 4*SZ64)       pack_frag(wdcn,ap + 2*SZ128 + 3*SZ64,       i - 2*SZ128 - 3*SZ64,  64, 64);
}

// ---------------------------------------------------------------------------
// NCHW fp32 -> NHWC bf16 (stride 64), all 3 input tensors in one dispatch.
// ---------------------------------------------------------------------------
__global__ __launch_bounds__(256) void nhwc3_k(const float* __restrict__ x,
                                               const float* __restrict__ xng,
                                               const float* __restrict__ offt,
                                               short* __restrict__ dx,
                                               short* __restrict__ dn,
                                               short* __restrict__ dof)
{
    __shared__ short s_t[128][72];
    const int tid = threadIdx.x;
    const int h = blockIdx.x;
    const int t = blockIdx.y >> 2, b = blockIdx.y & 3;
    const float* src = (t == 0) ? x : (t == 1) ? xng : offt;
    short* dst = (t == 0) ? dx : (t == 1) ? dn : dof;
    for (int i = tid; i < 64 * 128; i += 256) {
        int c = i >> 7, w = i & 127;
        s_t[w][c] = (short)f2bf(src[((size_t)(b * 64 + c)) * HWSZ + h * WW + w]);
    }
    __syncthreads();
    for (int i = tid; i < 128 * 32; i += 256) {
        int w = i >> 5, cp = i & 31;
        unsigned pk = (unsigned)(unsigned short)s_t[w][cp * 2]
                    | ((unsigned)(unsigned short)s_t[w][cp * 2 + 1] << 16);
        *(unsigned*)&dst[(((size_t)(b * 128 + h) * 128 + w) * 64) + cp * 2] = pk;
    }
}

// ---------------------------------------------------------------------------
// MFMA implicit-GEMM 3x3 SAME conv over NHWC bf16, K-chunk = 32.
// R5 structure: block = one (b,h) row, 4 waves = 2 oc-halves x 2 px-halves.
// New vs R5: XCD-swizzled linear grid (512); all-tap A-fragment prefetch
// issued after the barrier (one drain instead of 9 serialized stalls).
// ---------------------------------------------------------------------------
template<int NIC, int NOC, int OCS, int ACT, bool WH, bool WC>
__global__ __launch_bounds__(256, 3) void conv_k(
    const short* __restrict__ in1, const short* __restrict__ in2,
    const short* __restrict__ apack, const float* __restrict__ bias,
    short* __restrict__ outh, float* __restrict__ outc)
{
    constexpr int NCH = NIC / 32;
    __shared__ short s_x[3][130][40];   // [row][px+halo][32ch + pad]

    const int tid  = threadIdx.x;
    const int lane = tid & 63;
    const int wv   = tid >> 6;
    const int wo   = wv & 1;
    const int wp   = wv >> 1;
    const int n16  = lane & 15;
    const int kq   = lane >> 4;

    const int lin = blockIdx.x;                       // 512 blocks
    const int h   = (lin & 7) * 16 + ((lin >> 3) & 15);
    const int b   = lin >> 7;

    f4 acc[2][4];
#pragma unroll
    for (int t = 0; t < 2; ++t)
#pragma unroll
        for (int p = 0; p < 4; ++p) acc[t][p] = (f4){0.f, 0.f, 0.f, 0.f};

    const short* a_lane = apack + (size_t)lane * 8;

    for (int cc = 0; cc < NCH; ++cc) {
        const short* src; int c0;
        if (NIC == 128 && cc >= 2) { src = in2; c0 = (cc - 2) * 32; }
        else                       { src = in1; c0 = cc * 32; }
        __syncthreads();
        // stage 3 rows x 130 px x 32 ch, 16B per thread-iter (R5 verbatim)
        for (int i = tid; i < 1560; i += 256) {
            int row = i / 520, rem = i % 520;
            int px = rem >> 2, q = rem & 3;
            int gy = h - 1 + row, gx = px - 1;
            int4 v = {0, 0, 0, 0};
            if ((unsigned)gy < 128u && (unsigned)gx < 128u)
                v = *(const int4*)&src[(((size_t)(b * 128 + gy)) * 128 + gx) * 64 + c0 + q * 8];
            *(int4*)&s_x[row][px][q * 8] = v;
        }
        __syncthreads();

        if (wo * 32 < NOC) {
            // all-tap A prefetch: 18 independent global loads issued upfront
            bfrag af0[9], af1[9];
#pragma unroll
            for (int tap = 0; tap < 9; ++tap) {
                af0[tap] = *(const bfrag*)(a_lane + (size_t)(((wo * 2 + 0) * NCH + cc) * 9 + tap) * 512);
                af1[tap] = *(const bfrag*)(a_lane + (size_t)(((wo * 2 + 1) * NCH + cc) * 9 + tap) * 512);
            }
#pragma unroll
            for (int tap = 0; tap < 9; ++tap) {
                const int dy = tap / 3, dx = tap % 3;
#pragma unroll
                for (int p = 0; p < 4; ++p) {
                    bfrag bb = *(const bfrag*)&s_x[dy][wp * 64 + p * 16 + n16 + dx][kq * 8];
                    acc[0][p] = __builtin_amdgcn_mfma_f32_16x16x32_bf16(af0[tap], bb, acc[0][p], 0, 0, 0);
                    acc[1][p] = __builtin_amdgcn_mfma_f32_16x16x32_bf16(af1[tap], bb, acc[1][p], 0, 0, 0);
                }
            }
        }
    }

    // epilogue: C/D layout col=lane&15, row=(lane>>4)*4+reg (R5 verbatim)
#pragma unroll
    for (int oct = 0; oct < 2; ++oct) {
        int oc0 = wo * 32 + oct * 16 + kq * 4;
        if (oc0 < NOC) {
            float4 bv = *(const float4*)&bias[oc0];
#pragma unroll
            for (int p = 0; p < 4; ++p) {
                int col = wp * 64 + p * 16 + n16;
                float v0 = acc[oct][p][0] + bv.x;
                float v1 = acc[oct][p][1] + bv.y;
                float v2 = acc[oct][p][2] + bv.z;
                float v3 = acc[oct][p][3] + bv.w;
                if (ACT == 1) {
                    v0 = (v0 >= 0.f) ? v0 : 0.1f * v0;
                    v1 = (v1 >= 0.f) ? v1 : 0.1f * v1;
                    v2 = (v2 >= 0.f) ? v2 : 0.1f * v2;
                    v3 = (v3 >= 0.f) ? v3 : 0.1f * v3;
                }
                if (ACT == 2) {
                    v0 = fmaxf(v0, 0.f); v1 = fmaxf(v1, 0.f);
                    v2 = fmaxf(v2, 0.f); v3 = fmaxf(v3, 0.f);
                }
                if (WH) {
                    uint2 pk;
                    pk.x = (unsigned)f2bf(v0) | ((unsigned)f2bf(v1) << 16);
                    pk.y = (unsigned)f2bf(v2) | ((unsigned)f2bf(v3) << 16);
                    *(uint2*)&outh[(((size_t)(b * 128 + h)) * 128 + col) * OCS + oc0] = pk;
                }
                if (WC) {
                    size_t base = ((size_t)b * NOC) * HWSZ + h * WW + col;
                    outc[base + (size_t)(oc0 + 0) * HWSZ] = v0;
                    outc[base + (size_t)(oc0 + 1) * HWSZ] = v1;
                    outc[base + (size_t)(oc0 + 2) * HWSZ] = v2;
                    outc[base + (size_t)(oc0 + 3) * HWSZ] = v3;
                }
            }
        }
    }
}

// ---------------------------------------------------------------------------
// DCN per-pixel bilinear params from NHWC bf16 om (stride 32), once per px.
// (R5 verbatim)
// ---------------------------------------------------------------------------
__device__ inline void dcn_params(const short* __restrict__ omb, int h, int k, int tid,
                                  float (*s_pw)[4], int (*s_pi)[4])
{
    if (tid < 128) {
        int pix = tid;
        const short* o = omb + pix * 32;
        float oy = bf2f(o[k]);
        float ox = bf2f(o[9 + k]);
        float mv = bf2f(o[18 + k]);
        mv = 1.f / (1.f + expf(-mv));
        float py = (float)(h - 1 + (k / 3)) + oy;
        float px = (float)(pix - 1 + (k % 3)) + ox;
        float y0f = floorf(py), x0f = floorf(px);
        float ly = py - y0f, lx = px - x0f;
        int y0 = (int)y0f, x0 = (int)x0f;
        int y1 = y0 + 1, x1 = x0 + 1;
        float v00 = ((unsigned)y0 < 128u && (unsigned)x0 < 128u) ? 1.f : 0.f;
        float v01 = ((unsigned)y0 < 128u && (unsigned)x1 < 128u) ? 1.f : 0.f;
        float v10 = ((unsigned)y1 < 128u && (unsigned)x0 < 128u) ? 1.f : 0.f;
        float v11 = ((unsigned)y1 < 128u && (unsigned)x1 < 128u) ? 1.f : 0.f;
        int yc0 = min(max(y0, 0), 127), yc1 = min(max(y1, 0), 127);
        int xc0 = min(max(x0, 0), 127), xc1 = min(max(x1, 0), 127);
        s_pw[pix][0] = (1.f - ly) * (1.f - lx) * mv * v00;
        s_pw[pix][1] = (1.f - ly) * lx * mv * v01;
        s_pw[pix][2] = ly * (1.f - lx) * mv * v10;
        s_pw[pix][3] = ly * lx * mv * v11;
        s_pi[pix][0] = (yc0 * WW + xc0) * 64;
        s_pi[pix][1] = (yc0 * WW + xc1) * 64;
        s_pi[pix][2] = (yc1 * WW + xc0) * 64;
        s_pi[pix][3] = (yc1 * WW + xc1) * 64;
    }
}

// ---------------------------------------------------------------------------
// MFMA DCN (R5 structure: block = full row, 256 thr, wo x wp waves).
// New vs R5: XCD-swizzled grid; rolling-1 A-fragment prefetch.
// ---------------------------------------------------------------------------
__global__ __launch_bounds__(256, 4) void dcn_k(
    const short* __restrict__ xt, const short* __restrict__ om,
    const short* __restrict__ adcn, const float* __restrict__ bias,
    short* __restrict__ outh)
{
    __shared__ short s_samp[128][72];
    __shared__ float s_pw[128][4];
    __shared__ int   s_pi[128][4];

    const int tid  = threadIdx.x;
    const int lane = tid & 63;
    const int wv   = tid >> 6;
    const int wo   = wv & 1;
    const int wp   = wv >> 1;
    const int n16  = lane & 15;
    const int kq   = lane >> 4;

    const int lin = blockIdx.x;                       // 512 blocks
    const int h   = (lin & 7) * 16 + ((lin >> 3) & 15);
    const int b   = lin >> 7;

    f4 acc[2][4];
#pragma unroll
    for (int t = 0; t < 2; ++t)
#pragma unroll
        for (int p = 0; p < 4; ++p) acc[t][p] = (f4){0.f, 0.f, 0.f, 0.f};

    const short* a_lane = adcn + (size_t)lane * 8;
    const short* xb  = xt + (size_t)b * HWSZ * 64;
    const short* omb = om + ((size_t)(b * 128 + h)) * 128 * 32;

    dcn_params(omb, h, 0, tid, s_pw, s_pi);

    const int pp = lane >> 5;      // pixel-pair half
    const int cp = lane & 31;      // channel pair

    bfrag a_cur[2][2], a_nxt[2][2];      // [oi][ks]
#pragma unroll
    for (int oi = 0; oi < 2; ++oi)
#pragma unroll
        for (int ks = 0; ks < 2; ++ks)
            a_cur[oi][ks] = *(const bfrag*)(a_lane +
                (size_t)(((wo * 2 + oi) * 2 + ks) * 9 + 0) * 512);

    for (int k = 0; k < 9; ++k) {
        __syncthreads();   // params(k) visible; MFMA(k-1) done with s_samp
#pragma unroll 4
        for (int i = 0; i < 16; ++i) {
            int pix = i * 8 + wv * 2 + pp;
            float4 w = *(const float4*)s_pw[pix];
            int4  ix = *(const int4*)s_pi[pix];
            unsigned u00 = *(const unsigned*)&xb[ix.x + cp * 2];
            unsigned u01 = *(const unsigned*)&xb[ix.y + cp * 2];
            unsigned u10 = *(const unsigned*)&xb[ix.z + cp * 2];
            unsigned u11 = *(const unsigned*)&xb[ix.w + cp * 2];
            float lo = w.x * bf2f_lo(u00) + w.y * bf2f_lo(u01) + w.z * bf2f_lo(u10) + w.w * bf2f_lo(u11);
            float hi = w.x * bf2f_hi(u00) + w.y * bf2f_hi(u01) + w.z * bf2f_hi(u10) + w.w * bf2f_hi(u11);
            *(unsigned*)&s_samp[pix][cp * 2] = (unsigned)f2bf(lo) | ((unsigned)f2bf(hi) << 16);
        }
        __syncthreads();
        if (k < 8) {
            dcn_params(omb, h, k + 1, tid, s_pw, s_pi);
#pragma unroll
            for (int oi = 0; oi < 2; ++oi)
#pragma unroll
                for (int ks = 0; ks < 2; ++ks)
                    a_nxt[oi][ks] = *(const bfrag*)(a_lane +
                        (size_t)(((wo * 2 + oi) * 2 + ks) * 9 + (k + 1)) * 512);
        }
#pragma unroll
        for (int ks = 0; ks < 2; ++ks) {
#pragma unroll
            for (int p = 0; p < 4; ++p) {
                bfrag bb = *(const bfrag*)&s_samp[wp * 64 + p * 16 + n16][ks * 32 + kq * 8];
                acc[0][p] = __builtin_amdgcn_mfma_f32_16x16x32_bf16(a_cur[0][ks], bb, acc[0][p], 0, 0, 0);
                acc[1][p] = __builtin_amdgcn_mfma_f32_16x16x32_bf16(a_cur[1][ks], bb, acc[1][p], 0, 0, 0);
            }
        }
#pragma unroll
        for (int oi = 0; oi < 2; ++oi)
#pragma unroll
            for (int ks = 0; ks < 2; ++ks)
                a_cur[oi][ks] = a_nxt[oi][ks];
    }

    // epilogue: NHWC bf16, stride 64, no activation (R5 verbatim)
#pragma unroll
    for (int oct = 0; oct < 2; ++oct) {
        int oc0 = wo * 32 + oct * 16 + kq * 4;
        float4 bv = *(const float4*)&bias[oc0];
#pragma unroll
        for (int p = 0; p < 4; ++p) {
            int col = wp * 64 + p * 16 + n16;
            uint2 pk;
            pk.x = (unsigned)f2bf(acc[oct][p][0] + bv.x) | ((unsigned)f2bf(acc[oct][p][1] + bv.y) << 16);
            pk.y = (unsigned)f2bf(acc[oct][p][2] + bv.z) | ((unsigned)f2bf(acc[oct][p][3] + bv.w) << 16);
            *(uint2*)&outh[(((size_t)(b * 128 + h)) * 128 + col) * 64 + oc0] = pk;
        }
    }
}

// ---------------------------------------------------------------------------
extern "C" void kernel_launch(void* const* d_in, const int* in_sizes, int n_in,
                              void* d_out, int out_size, void* d_ws, size_t ws_size,
                              hipStream_t stream)
{
    const float* x      = (const float*)d_in[0];
    const float* xng    = (const float*)d_in[1];
    const float* offt   = (const float*)d_in[2];
    const float* w1     = (const float*)d_in[3];
    const float* b1     = (const float*)d_in[4];
    const float* w2     = (const float*)d_in[5];
    const float* b2     = (const float*)d_in[6];
    const float* w3     = (const float*)d_in[7];
    const float* b3     = (const float*)d_in[8];
    const float* wom    = (const float*)d_in[9];
    const float* bom    = (const float*)d_in[10];
    const float* wdcn   = (const float*)d_in[11];
    const float* bdcn   = (const float*)d_in[12];
    const float* wout   = (const float*)d_in[13];
    const float* bout   = (const float*)d_in[14];

    float* out0 = (float*)d_out;
    float* out1 = out0 + (size_t)4 * 64 * HWSZ;

    const size_t NB = (size_t)4 * HWSZ * 64;   // elements per NHWC bf16 tensor
    short* xtx = (short*)d_ws;        // x NHWC (conv1 + dcn)
    short* xtn = xtx + NB;            // x_neigh NHWC -> later o2 -> later align
    short* xto = xtn + NB;            // offset_t NHWC -> later om (stride 32)
    short* o1  = xto + NB;            // offset_1 -> later o3
    short* apk = o1 + NB;

    short* o2    = xtn;
    short* o3    = o1;
    short* omb   = xto;
    short* align = xtn;

    short* a1p  = apk;
    short* a2p  = apk + SZ128;
    short* a3p  = apk + 2 * SZ128;
    short* aomp = apk + 2 * SZ128 + SZ64;
    short* aout = apk + 2 * SZ128 + 2 * SZ64;
    short* adcn = apk + 2 * SZ128 + 3 * SZ64;

    pack_all_k<<<(2 * SZ128 + 4 * SZ64 + 255) / 256, 256, 0, stream>>>(
        w1, w2, w3, wom, wout, wdcn, apk);
    nhwc3_k<<<dim3(HH, 12), 256, 0, stream>>>(x, xng, offt, xtx, xtn, xto);

    // offset_1 = lrelu(conv(cat(x, x_neigh)))
    conv_k<128, 64, 64, 1, true, false><<<512, 256, 0, stream>>>(xtx, xtn, a1p, b1, o1, nullptr);
    // offset_2 = lrelu(conv(cat(offset_1, offset_t)))
    conv_k<128, 64, 64, 1, true, false><<<512, 256, 0, stream>>>(o1, xto, a2p, b2, o2, nullptr);
    // offset = lrelu(conv(offset_2)) -> NHWC for conv4 + NCHW fp32 output 1
    conv_k<64, 64, 64, 1, true, true><<<512, 256, 0, stream>>>(o2, nullptr, a3p, b3, o3, out1);
    // om = conv(offset), 27 ch, NHWC stride 32
    conv_k<64, 27, 32, 0, true, false><<<512, 256, 0, stream>>>(o3, nullptr, aomp, bom, omb, nullptr);
    // align = dcn_core(x, offsets, mask) -> NHWC bf16
    dcn_k<<<512, 256, 0, stream>>>(xtx, omb, adcn, bdcn, align);
    // out = relu(conv(align)) -> NCHW fp32 output 0
    conv_k<64, 64, 64, 2, false, true><<<512, 256, 0, stream>>>(align, nullptr, aout, bout, nullptr, out0);
}